// Round 12
// baseline (131.116 us; speedup 1.0000x reference)
//
#include <hip/hip_runtime.h>

// Involution2d, 3-kernel (R20: de-fused, barrier-free, LDS-free K1/K2).
// R18 FAILED correctness: kg lacked the batch dim -> all 4 batches raced on
// the same kern region. Fixed: kg indexed by (b*16+g)*7+q (29.4 MB).
// Rationale (R18): 4 structurally different fused K1s (R12..R16) all land
// 44-62us with ~75% stall (VALUBusy 23%, Mfma 6.7%, HBM 9%) -- the
// barrier-lockstep phase structure exposes memory latency block-wide.
// De-fuse so every wave runs free.
// K0 (unchanged R16): x f32 -> xp8 bf16 padded [b][oct][row70][col72][8ch],
//     rows 1152B-aligned; w -> bf16.
// K1 inv_gemm: R16's GEMM verbatim (64-reg tier, 8 waves/SIMD), epilogue
//     stores kern q-major to ws: kg[((b*16+g)*7+q)*4096 + px] uint4;
//     quad0/quad1 interleave into contiguous 512B runs (fully coalesced).
//     No LDS, no barriers.
// K2 inv_apply: 2048 blocks x 256thr; thread = 1 px x 1 oct. kern: 7 coalesced
//     uint4 loads. Taps: branch-free global from padded xp8 (11.5KB/block
//     footprint -> 17x L1 reuse). No LDS, no barriers, ~50 VGPR -> 32 waves/CU.
//     hi channel uses raw dword as f32 (low 16 bits sub-bf16 noise, <=0.4%).
// [R24: resubmit unchanged — R20..R23 benches were GPUAcquisitionTimeouts.]

#define B_   4
#define C_   256
#define G_   16
#define KK_  49
#define KS_  7
#define PD_  3

#define PROW  72
#define POCT  (70*PROW)                   // 5040 positions per (b,oct)
#define XP8_BYTES (B_*32*POCT*16)         // 10,321,920
#define WBF_OFF   XP8_BYTES
#define KERN_OFF  (WBF_OFF + 524288)      // wbf is 401,408 B
// kg: 4 b * 16 g * 7 q * 4096 px * 16 B = 29,360,128 B; ws total ~40.2 MB

typedef __attribute__((ext_vector_type(8))) short bf16x8;
typedef __attribute__((ext_vector_type(4))) float f32x4;
typedef unsigned short ushort_t;

__device__ inline unsigned f2bf(float f) {            // RNE fp32->bf16
    unsigned u = __float_as_uint(f);
    u += 0x7FFF + ((u >> 16) & 1);
    return u >> 16;
}

// ---------------- K0: x -> padded xp8 (channel-packed bf16); w -> bf16 ----------------
__global__ __launch_bounds__(256)
void cvt_xp8(const float* __restrict__ x, const float* __restrict__ wk,
             ushort_t* __restrict__ xp8, unsigned* __restrict__ wbf) {
    const int t = threadIdx.x;
    if (blockIdx.x == 64) {   // W convert: 100352 f32 pairs, 16 slices
        const int slice = blockIdx.z * 4 + blockIdx.y;
        const float2* wk2 = (const float2*)wk;
        const int base = slice * 6272;
        for (int k = t; k < 6272; k += 256) {
            float2 v = wk2[base + k];
            wbf[base + k] = f2bf(v.x) | (f2bf(v.y) << 16);
        }
        return;
    }
    if (blockIdx.x == 65) {   // zero pad rows {0,1,2,67,68,69} x 72 cols, 8 octs
        const int b  = blockIdx.z;
        const int o0 = blockIdx.y * 8;
        const uint4 z = make_uint4(0u, 0u, 0u, 0u);
        for (int e = t; e < 6 * PROW * 8; e += 256) {     // 3456
            const int o = e / (6 * PROW);
            const int f = e - o * (6 * PROW);
            const int r = f / PROW;
            const int c = f - r * PROW;
            const int row = (r < 3) ? r : 64 + r;         // 0,1,2,67,68,69
            *(uint4*)(xp8 + ((size_t)((b << 5) + o0 + o) * POCT + row * PROW + c) * 8) = z;
        }
        return;
    }
    __shared__ float tile[64][65];
    const int c0 = blockIdx.y * 64;       // 8 octs per slice
    const int b  = blockIdx.z;
    const int px_r = t & 63;
    #pragma unroll
    for (int i = 0; i < 16; ++i) {
        int ch = (t >> 6) + i * 4;
        tile[ch][px_r] = x[((size_t)(b * C_ + c0 + ch) << 12) + blockIdx.x * 64 + px_r];
    }
    __syncthreads();
    const int lane = t & 63;
    const int ob = t >> 6;                // 0..3
    #pragma unroll
    for (int jj = 0; jj < 2; ++jj) {
        const int j = ob + jj * 4;        // oct within slice, 0..7
        ushort_t* rowbase = xp8 + ((size_t)((b << 5) + (c0 >> 3) + j) * POCT
                                   + (blockIdx.x + 3) * PROW) * 8;
        #pragma unroll
        for (int cc = 0; cc < 2; ++cc) {
            const int col = lane + cc * 64;
            if (col < PROW) {
                uint4 v = make_uint4(0u, 0u, 0u, 0u);
                if (col >= 3 && col < 67) {
                    const int p = col - 3;
                    unsigned u[4];
                    #pragma unroll
                    for (int k2 = 0; k2 < 4; ++k2) {
                        float a0 = tile[j * 8 + 2 * k2][p];
                        float a1 = tile[j * 8 + 2 * k2 + 1][p];
                        u[k2] = f2bf(a0) | (f2bf(a1) << 16);
                    }
                    v = make_uint4(u[0], u[1], u[2], u[3]);
                }
                *(uint4*)(rowbase + col * 8) = v;   // full aligned 1152B row
            }
        }
    }
}

// ---------------- K1: GEMM -> kg (global, q-major, per (b,g)) ----------------
__global__ __launch_bounds__(512, 8)
void inv_gemm(const ushort_t* __restrict__ xp8,
              const ushort_t* __restrict__ wbf,
              const float* __restrict__ bk,
              unsigned* __restrict__ kg) {
    const int bid  = blockIdx.x;
    const int g    = bid >> 6;
    const int b    = (bid >> 4) & 3;
    const int tile = bid & 15;
    const int p0   = tile * 256;

    const int tid  = threadIdx.x;
    const int wv   = tid >> 6;                // 0..7
    const int ln15 = tid & 15;
    const int quad = (tid & 63) >> 4;

    f32x4 acc[8];
    #pragma unroll
    for (int i = 0; i < 8; ++i) acc[i] = (f32x4){0.f, 0.f, 0.f, 0.f};

    const char* bbase = (const char*)xp8 + (size_t)b * 32 * POCT * 16;
    const char* abase = (const char*)wbf + (size_t)g * KK_ * 512;

    int vb0, vb1;
    {
        int gi0 = p0 + wv * 32 + ln15;             // nt=0 pixel index
        int gi1 = gi0 + 16;                        // nt=1
        vb0 = (quad * POCT + ((gi0 >> 6) + 3) * PROW + 3 + (gi0 & 63)) * 16;
        vb1 = (quad * POCT + ((gi1 >> 6) + 3) * PROW + 3 + (gi1 & 63)) * 16;
    }
    int va  = ln15 * 512 + quad * 16;         // mt 0..2: + mt*8192 via s-base
    const int va3 = 48 * 512 + quad * 16;     // mt 3: row clamped to 48

    #pragma unroll
    for (int k = 0; k < 8; ++k) {
        bf16x8 af0 = *(const bf16x8*)(abase + va);
        bf16x8 af1 = *(const bf16x8*)(abase + 8192 + va);
        bf16x8 af2 = *(const bf16x8*)(abase + 16384 + va);
        bf16x8 af3 = *(const bf16x8*)(abase + va3 + k * 64);
        bf16x8 bf0 = *(const bf16x8*)(bbase + vb0);
        bf16x8 bf1 = *(const bf16x8*)(bbase + vb1);
        acc[0] = __builtin_amdgcn_mfma_f32_16x16x32_bf16(af0, bf0, acc[0], 0, 0, 0);
        acc[1] = __builtin_amdgcn_mfma_f32_16x16x32_bf16(af0, bf1, acc[1], 0, 0, 0);
        acc[2] = __builtin_amdgcn_mfma_f32_16x16x32_bf16(af1, bf0, acc[2], 0, 0, 0);
        acc[3] = __builtin_amdgcn_mfma_f32_16x16x32_bf16(af1, bf1, acc[3], 0, 0, 0);
        acc[4] = __builtin_amdgcn_mfma_f32_16x16x32_bf16(af2, bf0, acc[4], 0, 0, 0);
        acc[5] = __builtin_amdgcn_mfma_f32_16x16x32_bf16(af2, bf1, acc[5], 0, 0, 0);
        acc[6] = __builtin_amdgcn_mfma_f32_16x16x32_bf16(af3, bf0, acc[6], 0, 0, 0);
        acc[7] = __builtin_amdgcn_mfma_f32_16x16x32_bf16(af3, bf1, acc[7], 0, 0, 0);
        va  += 64;                              // +32 channels
        vb0 += 4 * POCT * 16; vb1 += 4 * POCT * 16;   // +4 octs
    }

    // ---- epilogue: acc -> kg[((b*16+g)*7+q7)*4096 + p] uint4 region ----
    // q7 = mt*2 + (quad>>1); dword pair (quad&1)*2. Within a wave, quad0/quad1
    // interleave 8B halves of consecutive 16B cells -> contiguous 512B runs.
    const int kbg = b * 16 + g;
    #pragma unroll
    for (int mt = 0; mt < 3; ++mt) {                      // m <= 47
        const int m0 = mt * 16 + quad * 4;
        const float b0 = bk[g * KK_ + m0],     b1 = bk[g * KK_ + m0 + 1];
        const float b2 = bk[g * KK_ + m0 + 2], b3 = bk[g * KK_ + m0 + 3];
        const int q7 = mt * 2 + (quad >> 1);
        #pragma unroll
        for (int nt = 0; nt < 2; ++nt) {
            const int p = p0 + wv * 32 + nt * 16 + ln15;
            uint2 d;
            d.x = f2bf(acc[mt * 2 + nt][0] + b0) | (f2bf(acc[mt * 2 + nt][1] + b1) << 16);
            d.y = f2bf(acc[mt * 2 + nt][2] + b2) | (f2bf(acc[mt * 2 + nt][3] + b3) << 16);
            *(uint2*)&kg[((((kbg * 7 + q7) << 12) + p) << 2) + (quad & 1) * 2] = d;
        }
    }
    if (quad == 0) {                                      // mt=3: only m=48 valid
        const float b48 = bk[g * KK_ + 48];
        #pragma unroll
        for (int nt = 0; nt < 2; ++nt) {
            const int p = p0 + wv * 32 + nt * 16 + ln15;
            kg[(((kbg * 7 + 6) << 12) + p) << 2] = f2bf(acc[6 + nt][0] + b48);   // lo=m48
        }
    }
}

// ---------------- K2: apply (barrier-free, LDS-free) ----------------
__global__ __launch_bounds__(256, 8)
void inv_apply(const ushort_t* __restrict__ xp8,
               const unsigned* __restrict__ kg,
               float* __restrict__ out) {
    const int bid = blockIdx.x;
    const int ho  = bid & 1;
    const int tq  = (bid >> 1) & 15;
    const int b   = (bid >> 5) & 3;
    const int g   = bid >> 7;
    const int tid = threadIdx.x;
    const int px  = tq * 256 + tid;
    const int row = px >> 6, col = px & 63;

    // my pixel's 49 kern values: 7 coalesced uint4 loads (q=6: only .x used)
    const int kbg = b * 16 + g;
    unsigned kd[28];
    #pragma unroll
    for (int q = 0; q < 7; ++q) {
        uint4 h = *(const uint4*)&kg[(((kbg * 7 + q) << 12) + px) << 2];
        kd[4*q] = h.x; kd[4*q+1] = h.y; kd[4*q+2] = h.z; kd[4*q+3] = h.w;
    }

    // taps: branch-free from padded xp8; per-block footprint 10 rows x 1152B
    const char* hb = (const char*)xp8
        + ((size_t)(b * 32 + 2 * g + ho) * POCT + row * PROW + col) * 16;

    float a[8];
    #pragma unroll
    for (int q = 0; q < 8; ++q) a[q] = 0.f;
    #pragma unroll
    for (int kh = 0; kh < KS_; ++kh) {
        const uint4* hr = (const uint4*)(hb + (size_t)kh * PROW * 16);
        #pragma unroll
        for (int kw = 0; kw < KS_; ++kw) {
            uint4 hv = hr[kw];
            const int t49 = kh * KS_ + kw;
            unsigned d = kd[t49 >> 1];
            float kk = __uint_as_float((t49 & 1) ? (d & 0xffff0000u) : (d << 16));
            a[0] = fmaf(__uint_as_float(hv.x << 16), kk, a[0]);
            a[1] = fmaf(__uint_as_float(hv.x),       kk, a[1]);
            a[2] = fmaf(__uint_as_float(hv.y << 16), kk, a[2]);
            a[3] = fmaf(__uint_as_float(hv.y),       kk, a[3]);
            a[4] = fmaf(__uint_as_float(hv.z << 16), kk, a[4]);
            a[5] = fmaf(__uint_as_float(hv.z),       kk, a[5]);
            a[6] = fmaf(__uint_as_float(hv.w << 16), kk, a[6]);
            a[7] = fmaf(__uint_as_float(hv.w),       kk, a[7]);
        }
    }
    const size_t o = ((size_t)(b * C_ + g * 16 + ho * 8) << 12) + px;
    #pragma unroll
    for (int q = 0; q < 8; ++q)
        out[o + ((size_t)q << 12)] = a[q];
}

extern "C" void kernel_launch(void* const* d_in, const int* in_sizes, int n_in,
                              void* d_out, int out_size, void* d_ws, size_t ws_size,
                              hipStream_t stream) {
    const float* x  = (const float*)d_in[0];
    const float* wk = (const float*)d_in[1];
    const float* bk = (const float*)d_in[2];
    float* o = (float*)d_out;

    ushort_t* xp8 = (ushort_t*)d_ws;
    unsigned* wbf = (unsigned*)((char*)d_ws + WBF_OFF);
    unsigned* kg  = (unsigned*)((char*)d_ws + KERN_OFF);

    cvt_xp8<<<dim3(66, 4, B_), dim3(256), 0, stream>>>(x, wk, xp8, wbf);
    inv_gemm<<<dim3(1024), dim3(512), 0, stream>>>(
        xp8, (const ushort_t*)wbf, bk, kg);
    inv_apply<<<dim3(2048), dim3(256), 0, stream>>>(xp8, kg, o);
}

// Round 14
// 117.962 us; speedup vs baseline: 1.1115x; 1.1115x over previous
//
#include <hip/hip_runtime.h>

// Involution2d, 2-kernel (R25: unpadded xp8 + fused 64-reg inv, masked taps).
// LEDGER (2-measured-term subtractions): unpadded K0 = 5.3us (R2); padded K0
// = 23.1us (R3) -- the padded layout costs ~18us for unknown reasons. The
// best measured inv is R15's fused 46.8us (64-reg GEMM, 1 barrier, taps
// direct from global). De-fused R20 = worse (gemm+apply ~64 + kg traffic).
// So: K0 = R13's measured 5.3us kernel VERBATIM (unpadded [b][oct][4096px][8ch]);
// inv = R15 structure on unpadded layout: OOB taps via clamped address +
// kk-cndmask-to-zero (wave-coherent: each wave spans one image row).
// K1: 512 thr, LB(512,8) -> 64-reg tier, 32 waves/CU, grid 1024 = 4/CU.
//   GEMM: single-buffered frags, s-base + voffset; kern -> kq LDS transposed
//   [7][256][16B] (conflict-free, verified R5); ONE barrier; apply: 49 global
//   uint4 taps (L1-hot), hi channel uses raw dword as f32 (<=0.4% rel noise).
// [R26: resubmit unchanged — R25 bench was a GPUAcquisitionTimeout, no data.]

#define B_   4
#define C_   256
#define G_   16
#define KK_  49
#define KS_  7
#define PD_  3

#define XP8_BYTES (B_*32*4096*8*2)       // 8,388,608
#define WBF_OFF   XP8_BYTES

typedef __attribute__((ext_vector_type(8))) short bf16x8;
typedef __attribute__((ext_vector_type(4))) float f32x4;
typedef unsigned short ushort_t;

__device__ inline unsigned f2bf(float f) {            // RNE fp32->bf16
    unsigned u = __float_as_uint(f);
    u += 0x7FFF + ((u >> 16) & 1);
    return u >> 16;
}

// ---------------- K0: x -> xp8 (channel-packed bf16); w -> bf16 ----------------
// VERBATIM the R13 kernel measured at ~5.3us (R2 run).
__global__ __launch_bounds__(256)
void cvt_xp8(const float* __restrict__ x, const float* __restrict__ wk,
             ushort_t* __restrict__ xp8, unsigned* __restrict__ wbf) {
    const int t = threadIdx.x;
    if (blockIdx.x == 64) {   // W convert: 100352 f32 pairs, 16 slices
        const int slice = blockIdx.z * 4 + blockIdx.y;
        const float2* wk2 = (const float2*)wk;
        const int base = slice * 6272;
        for (int k = t; k < 6272; k += 256) {
            float2 v = wk2[base + k];
            wbf[base + k] = f2bf(v.x) | (f2bf(v.y) << 16);
        }
        return;
    }
    __shared__ float tile[64][65];
    const int p0 = blockIdx.x * 64;
    const int c0 = blockIdx.y * 64;       // 8 octs per slice
    const int b  = blockIdx.z;
    const int px_r = t & 63;
    #pragma unroll
    for (int i = 0; i < 16; ++i) {
        int ch = (t >> 6) + i * 4;
        tile[ch][px_r] = x[((size_t)(b * C_ + c0 + ch) << 12) + p0 + px_r];
    }
    __syncthreads();
    const int px = t & 63;
    const int ob = t >> 6;                // 0..3
    #pragma unroll
    for (int jj = 0; jj < 2; ++jj) {
        const int j = ob + jj * 4;        // oct within slice, 0..7
        unsigned u[4];
        #pragma unroll
        for (int k2 = 0; k2 < 4; ++k2) {
            float a0 = tile[j * 8 + 2 * k2][px];
            float a1 = tile[j * 8 + 2 * k2 + 1][px];
            u[k2] = f2bf(a0) | (f2bf(a1) << 16);
        }
        ushort_t* dst = xp8 + (((size_t)((b << 5) + (c0 >> 3) + j) << 12) + p0 + px) * 8;
        *(uint4*)dst = make_uint4(u[0], u[1], u[2], u[3]);
    }
}

// ---------------- K1: fused GEMM + apply (unpadded, masked taps) ----------------
__global__ __launch_bounds__(512, 8)
void inv_fused(const ushort_t* __restrict__ xp8,
               const ushort_t* __restrict__ wbf,
               const float* __restrict__ bk,
               float* __restrict__ out) {
    __shared__ unsigned kq[7 * 256 * 4];      // 28,672 B  kq[q][pixel][4dw]

    const int bid  = blockIdx.x;
    const int g    = bid >> 6;
    const int b    = (bid >> 4) & 3;
    const int tile = bid & 15;
    const int gy0  = tile * 4;
    const int p0   = tile * 256;

    const int tid  = threadIdx.x;
    const int wv   = tid >> 6;                // 0..7
    const int ln15 = tid & 15;
    const int quad = (tid & 63) >> 4;

    // ---- GEMM: wave wv owns n-cols p0+wv*32 (2 n-tiles) x 4 m-tiles ----
    f32x4 acc[8];
    #pragma unroll
    for (int i = 0; i < 8; ++i) acc[i] = (f32x4){0.f, 0.f, 0.f, 0.f};

    const char* bbase = (const char*)xp8 + ((size_t)b << 21);   // 32 octs * 64KB
    const char* abase = (const char*)wbf + (size_t)g * KK_ * 512;

    int vb0;
    {
        int gi0 = p0 + wv * 32 + ln15;             // nt=0 pixel index
        vb0 = ((quad << 12) + gi0) << 4;           // (quad*4096 + gi0)*16
    }
    int vb1 = vb0 + 256;                           // gi1 = gi0+16 -> +256B
    int va  = ln15 * 512 + quad * 16;              // mt 0..2: + mt*8192 via s-base
    const int va3 = 48 * 512 + quad * 16;          // mt 3: row clamped to 48

    #pragma unroll
    for (int k = 0; k < 8; ++k) {
        bf16x8 af0 = *(const bf16x8*)(abase + va);
        bf16x8 af1 = *(const bf16x8*)(abase + 8192 + va);
        bf16x8 af2 = *(const bf16x8*)(abase + 16384 + va);
        bf16x8 af3 = *(const bf16x8*)(abase + va3 + k * 64);
        bf16x8 bf0 = *(const bf16x8*)(bbase + vb0);
        bf16x8 bf1 = *(const bf16x8*)(bbase + vb1);
        acc[0] = __builtin_amdgcn_mfma_f32_16x16x32_bf16(af0, bf0, acc[0], 0, 0, 0);
        acc[1] = __builtin_amdgcn_mfma_f32_16x16x32_bf16(af0, bf1, acc[1], 0, 0, 0);
        acc[2] = __builtin_amdgcn_mfma_f32_16x16x32_bf16(af1, bf0, acc[2], 0, 0, 0);
        acc[3] = __builtin_amdgcn_mfma_f32_16x16x32_bf16(af1, bf1, acc[3], 0, 0, 0);
        acc[4] = __builtin_amdgcn_mfma_f32_16x16x32_bf16(af2, bf0, acc[4], 0, 0, 0);
        acc[5] = __builtin_amdgcn_mfma_f32_16x16x32_bf16(af2, bf1, acc[5], 0, 0, 0);
        acc[6] = __builtin_amdgcn_mfma_f32_16x16x32_bf16(af3, bf0, acc[6], 0, 0, 0);
        acc[7] = __builtin_amdgcn_mfma_f32_16x16x32_bf16(af3, bf1, acc[7], 0, 0, 0);
        va  += 64;                                 // +32 channels
        vb0 += 4 * 4096 * 16; vb1 += 4 * 4096 * 16;   // +4 octs
    }

    // ---- epilogue: acc -> kq[q7=mt*2+(quad>>1)][p], dword pair (quad&1)*2 ----
    #pragma unroll
    for (int mt = 0; mt < 3; ++mt) {                      // m <= 47
        const int m0 = mt * 16 + quad * 4;
        const float b0 = bk[g * KK_ + m0],     b1 = bk[g * KK_ + m0 + 1];
        const float b2 = bk[g * KK_ + m0 + 2], b3 = bk[g * KK_ + m0 + 3];
        const int q7 = mt * 2 + (quad >> 1);
        #pragma unroll
        for (int nt = 0; nt < 2; ++nt) {
            const int p = wv * 32 + nt * 16 + ln15;
            uint2 d;
            d.x = f2bf(acc[mt * 2 + nt][0] + b0) | (f2bf(acc[mt * 2 + nt][1] + b1) << 16);
            d.y = f2bf(acc[mt * 2 + nt][2] + b2) | (f2bf(acc[mt * 2 + nt][3] + b3) << 16);
            *(uint2*)&kq[(q7 * 256 + p) * 4 + (quad & 1) * 2] = d;
        }
    }
    if (quad == 0) {                                      // mt=3: only m=48 valid
        const float b48 = bk[g * KK_ + 48];
        #pragma unroll
        for (int nt = 0; nt < 2; ++nt) {
            const int p = wv * 32 + nt * 16 + ln15;
            kq[(6 * 256 + p) * 4] = f2bf(acc[6 + nt][0] + b48);   // lo=m48
        }
    }
    __syncthreads();   // the only barrier: kq complete

    // ---- my pixel's 49 kern values: 7x conflict-free ds_read_b128 ----
    const int pix = tid & 255;
    const int ho  = tid >> 8;
    unsigned kd[28];
    #pragma unroll
    for (int q = 0; q < 7; ++q) {
        uint4 h = *(const uint4*)&kq[(q * 256 + pix) * 4];
        kd[4*q] = h.x; kd[4*q+1] = h.y; kd[4*q+2] = h.z; kd[4*q+3] = h.w;
    }

    // ---- apply: taps direct from unpadded xp8, clamped addr + kk-masking ----
    const int py = pix >> 6, pxx = pix & 63;
    const char* obse = (const char*)xp8 + ((size_t)((b << 5) + 2 * g + ho) << 16);

    float a[8];
    #pragma unroll
    for (int q = 0; q < 8; ++q) a[q] = 0.f;
    #pragma unroll
    for (int kh = 0; kh < KS_; ++kh) {
        const int sy  = gy0 + py + kh - PD_;
        const int csy = min(max(sy, 0), 63);
        const bool oky = (sy == csy);
        const char* hrow = obse + ((size_t)csy << 10);    // 64 cells * 16B
        #pragma unroll
        for (int kw = 0; kw < KS_; ++kw) {
            const int sx  = pxx + kw - PD_;
            const int csx = min(max(sx, 0), 63);
            uint4 hv = *(const uint4*)(hrow + (csx << 4));
            const int t49 = kh * KS_ + kw;
            unsigned d = kd[t49 >> 1];
            float kk = __uint_as_float((t49 & 1) ? (d & 0xffff0000u) : (d << 16));
            kk = (oky && sx == csx) ? kk : 0.f;           // zero OOB taps
            a[0] = fmaf(__uint_as_float(hv.x << 16), kk, a[0]);
            a[1] = fmaf(__uint_as_float(hv.x),       kk, a[1]);
            a[2] = fmaf(__uint_as_float(hv.y << 16), kk, a[2]);
            a[3] = fmaf(__uint_as_float(hv.y),       kk, a[3]);
            a[4] = fmaf(__uint_as_float(hv.z << 16), kk, a[4]);
            a[5] = fmaf(__uint_as_float(hv.z),       kk, a[5]);
            a[6] = fmaf(__uint_as_float(hv.w << 16), kk, a[6]);
            a[7] = fmaf(__uint_as_float(hv.w),       kk, a[7]);
        }
    }
    const size_t o = ((size_t)(b * C_ + g * 16 + ho * 8) << 12) + p0 + pix;
    #pragma unroll
    for (int q = 0; q < 8; ++q)
        out[o + ((size_t)q << 12)] = a[q];
}

extern "C" void kernel_launch(void* const* d_in, const int* in_sizes, int n_in,
                              void* d_out, int out_size, void* d_ws, size_t ws_size,
                              hipStream_t stream) {
    const float* x  = (const float*)d_in[0];
    const float* wk = (const float*)d_in[1];
    const float* bk = (const float*)d_in[2];
    float* o = (float*)d_out;

    ushort_t* xp8 = (ushort_t*)d_ws;
    unsigned* wbf = (unsigned*)((char*)d_ws + WBF_OFF);

    cvt_xp8<<<dim3(65, 4, B_), dim3(256), 0, stream>>>(x, wk, xp8, wbf);
    inv_fused<<<dim3(1024), dim3(512), 0, stream>>>(
        xp8, (const ushort_t*)wbf, bk, o);
}